// Round 3
// baseline (161.932 us; speedup 1.0000x reference)
//
#include <hip/hip_runtime.h>

// DiscriminatorIndependent: 1024 tiny MLPs (2->4->1, relu), B=16384.
//
// R1-R5: register-resident payload loads are latency-serialized by the
// compiler -> async global->LDS staging (global_load_lds width=16) is the
// right structure. R6: occupancy 32->60% changed NOTHING (41.5us both) ->
// not latency-bound. The invariant: total CU-port traffic. R6 moved
// 128MB payload + 139MB re-fetched params = 267MB / 41.5us = 6.4 TB/s =
// the per-CU load-port ceiling (~10B/cy/CU). The roofline was half full
// of redundant param bytes.
//
// R7: persistent blocks. Grid = 2048 (8/CU, wave-limited residency); each
// block loads its quarter's params ONCE into registers (17 regs) and loops
// over 8 row-tiles with double-buffered LDS staging (stage t+1 while
// computing t; the single __syncthreads per tile drains loads issued a
// full compute-phase ago). Param traffic 139MB -> 34MB. Reduction: per-wave
// shuffle partials atomicAdd directly (no cross-wave LDS combine, no 2nd
// barrier). Traffic 267 -> 162MB -> predict ~27us.

constexpr int N_MLP = 1024;
constexpr int BATCH = 16384;
constexpr int ROWS = 4;          // batch rows per tile
constexpr int NTHREADS = 256;    // 4 waves; covers QN MLPs
constexpr int QN = 256;          // MLPs per block (quarter of N)
constexpr int NQ = N_MLP / QN;   // 4 quarters
constexpr int NBLK = 2048;       // persistent: 8 blocks/CU x 256 CU
constexpr int GROUPS = NBLK / NQ;               // 512 row-groups
constexpr int TILES = (BATCH / ROWS) / GROUPS;  // 8 tiles per block

typedef __attribute__((address_space(3))) void lds_void;
typedef const __attribute__((address_space(1))) void gbl_void;

__global__ __launch_bounds__(256)
void zero_out_kernel(float* __restrict__ out) {
    out[blockIdx.x * 256 + threadIdx.x] = 0.0f;
}

__global__ __launch_bounds__(NTHREADS, 8)
void disc_mlp_kernel(const float* __restrict__ x,
                     const float* __restrict__ xa,
                     const float* __restrict__ W1,
                     const float* __restrict__ b1,
                     const float* __restrict__ W2,
                     const float* __restrict__ b2,
                     float* __restrict__ out)
{
    __shared__ float xbuf[2][ROWS * QN];   // 2 x 4 KB
    __shared__ float abuf[2][ROWS * QN];   // 2 x 4 KB   -> 16 KB total

    const int t    = threadIdx.x;
    const int lane = t & 63;
    const int wave = t >> 6;
    const int q    = blockIdx.x & (NQ - 1);  // n-quarter
    const int g    = blockIdx.x >> 2;        // row-group (0..511)
    const int n    = q * QN + t;             // this thread's MLP

    // ---- params once per persistent block -> 17 registers ----
    const float4 p0 = reinterpret_cast<const float4*>(W1)[(size_t)n * 2];
    const float4 p1 = reinterpret_cast<const float4*>(W1)[(size_t)n * 2 + 1];
    const float4 bb = reinterpret_cast<const float4*>(b1)[n];
    const float4 ww = reinterpret_cast<const float4*>(W2)[n];
    const float  b2r = b2[n];

    const float A[4]   = {p0.x, p0.z, p1.x, p1.z};
    const float C[4]   = {p0.y, p0.w, p1.y, p1.w};
    const float B1r[4] = {bb.x, bb.y, bb.z, bb.w};
    const float V[4]   = {ww.x, ww.y, ww.z, ww.w};

    const float* gx = x  + q * QN;
    const float* ga = xa + q * QN;

    // Wave w stages row w of the tile (x and xa): 64 lanes x 16B = 1 KB each.
    auto stage = [&](int it, int buf) {
        const int b0 = (g + it * GROUPS) * ROWS;
        const size_t off = (size_t)(b0 + wave) * N_MLP + lane * 4;
        __builtin_amdgcn_global_load_lds((gbl_void*)(gx + off),
                                         (lds_void*)&xbuf[buf][wave * QN + lane * 4],
                                         16, 0, 0);
        __builtin_amdgcn_global_load_lds((gbl_void*)(ga + off),
                                         (lds_void*)&abuf[buf][wave * QN + lane * 4],
                                         16, 0, 0);
    };

    stage(0, 0);
    __syncthreads();   // tile 0 resident

    for (int it = 0; it < TILES; ++it) {
        const int cur = it & 1;
        if (it + 1 < TILES) stage(it + 1, cur ^ 1);   // async prefetch

        const int b0 = (g + it * GROUPS) * ROWS;

        float acc[ROWS];
#pragma unroll
        for (int r = 0; r < ROWS; ++r) {
            const float xe  = xbuf[cur][r * QN + t];
            const float xae = abuf[cur][r * QN + t];
            float s = b2r;
#pragma unroll
            for (int j = 0; j < 4; ++j) {
                float h = fmaf(A[j], xe, fmaf(C[j], xae, B1r[j]));
                h = fmaxf(h, 0.0f);
                s = fmaf(V[j], h, s);
            }
            acc[r] = s;
        }

        // per-wave reduce each row; wave partial -> atomicAdd (no 2nd barrier)
#pragma unroll
        for (int r = 0; r < ROWS; ++r) {
            float v = acc[r];
            v += __shfl_down(v, 32);
            v += __shfl_down(v, 16);
            v += __shfl_down(v, 8);
            v += __shfl_down(v, 4);
            v += __shfl_down(v, 2);
            v += __shfl_down(v, 1);
            if (lane == 0)
                atomicAdd(out + b0 + r, v * (1.0f / (float)N_MLP));
        }

        __syncthreads();   // all reads of buf[cur] done; prefetch drained
    }
}

extern "C" void kernel_launch(void* const* d_in, const int* in_sizes, int n_in,
                              void* d_out, int out_size, void* d_ws, size_t ws_size,
                              hipStream_t stream) {
    const float* x  = (const float*)d_in[0];
    const float* xa = (const float*)d_in[1];
    const float* W1 = (const float*)d_in[2];
    const float* b1 = (const float*)d_in[3];
    const float* W2 = (const float*)d_in[4];
    const float* b2 = (const float*)d_in[5];
    float* out = (float*)d_out;

    zero_out_kernel<<<BATCH / 256, 256, 0, stream>>>(out);
    disc_mlp_kernel<<<NBLK, NTHREADS, 0, stream>>>(x, xa, W1, b1, W2, b2, out);
}

// Round 4
// 154.777 us; speedup vs baseline: 1.0462x; 1.0462x over previous
//
#include <hip/hip_runtime.h>

// DiscriminatorIndependent: 1024 tiny MLPs (2->4->1, relu), B=16384.
//
// R1-R5: payload must go through async global->LDS staging (gload_lds w=16);
// register-destination loads get latency-serialized by the compiler.
// R6: occupancy 32->60% changed nothing -> not latency-hiding-bound.
// R7 FALSIFIED the traffic theory: 162MB total ran SLOWER (51.7us) because
// per-tile atomicAdds (262K, cross-XCD) sat in every vmcnt drain; WRITE_SIZE
// 256KB->8.2MB. Persistent grids also pin dispatch imbalance.
//
// R8 theory: the R0/R6-invariant is DS-pipe work (~49Kcy/CU = 20us: scalar
// ds_read_b32 payload reads + 6 ds_bpermute-shfl per row per thread), ~50%
// DS occupancy. Attack it structurally, keeping R6's proven shape:
//   k=2 MLPs/thread (QN=512): b64 payload reads, half the blocks -> half
//     the per-CU shuffle work (~25Kcy).
//   TILES=2 sequential row-tiles per block, params loaded once: param
//     traffic 139->71MB. Atomics ONLY in the epilogue (2/element), never
//     inside a staging drain.

constexpr int N_MLP = 1024;
constexpr int BATCH = 16384;
constexpr int ROWS = 8;            // batch rows per tile
constexpr int NTHREADS = 256;      // 4 waves
constexpr int K = 2;               // MLPs per thread
constexpr int QN = NTHREADS * K;   // 512 MLPs per block
constexpr int NQ = N_MLP / QN;     // 2 halves
constexpr int TILES = 2;           // row-tiles per block (param reuse)
constexpr int NBLK = (BATCH / (ROWS * TILES)) * NQ;   // 2048

typedef __attribute__((address_space(3))) void lds_void;
typedef const __attribute__((address_space(1))) void gbl_void;

__global__ __launch_bounds__(256)
void zero_out_kernel(float* __restrict__ out) {
    out[blockIdx.x * 256 + threadIdx.x] = 0.0f;
}

__global__ __launch_bounds__(NTHREADS, 4)
void disc_mlp_kernel(const float* __restrict__ x,
                     const float* __restrict__ xa,
                     const float* __restrict__ W1,
                     const float* __restrict__ b1,
                     const float* __restrict__ W2,
                     const float* __restrict__ b2,
                     float* __restrict__ out)
{
    __shared__ float xbuf[ROWS * QN];   // 16 KB
    __shared__ float abuf[ROWS * QN];   // 16 KB
    __shared__ float red[NTHREADS / 64][ROWS];

    const int t    = threadIdx.x;
    const int lane = t & 63;
    const int wave = t >> 6;
    const int q    = blockIdx.x & (NQ - 1);   // n-half
    const int g    = blockIdx.x >> 1;         // row-group (0..1023)
    const int n0   = q * QN + t * K;          // first of this thread's 2 MLPs

    // ---- params for 2 consecutive MLPs -> 34 regs, loaded once per block ----
    // W1[m]: 8 floats [h][e]: wa=(h0e0,h0e1,h1e0,h1e1) wb=(h2e0,h2e1,h3e0,h3e1)
    const float4 wa0 = reinterpret_cast<const float4*>(W1)[(size_t)n0 * 2];
    const float4 wb0 = reinterpret_cast<const float4*>(W1)[(size_t)n0 * 2 + 1];
    const float4 wa1 = reinterpret_cast<const float4*>(W1)[(size_t)(n0 + 1) * 2];
    const float4 wb1 = reinterpret_cast<const float4*>(W1)[(size_t)(n0 + 1) * 2 + 1];
    const float4 b10 = reinterpret_cast<const float4*>(b1)[n0];
    const float4 b11 = reinterpret_cast<const float4*>(b1)[n0 + 1];
    const float4 w20 = reinterpret_cast<const float4*>(W2)[n0];
    const float4 w21 = reinterpret_cast<const float4*>(W2)[n0 + 1];
    const float2 b2v = reinterpret_cast<const float2*>(b2)[n0 >> 1];
    const float bsum = b2v.x + b2v.y;

    const float* gx = x  + q * QN;
    const float* ga = xa + q * QN;

    for (int it = 0; it < TILES; ++it) {
        const int b0 = (g * TILES + it) * ROWS;

        // ---- async global->LDS staging: wave w stages rows 2w,2w+1 ----
        // per (wave,row,array): 512 floats = 2 chunks of 64 lanes x 16B.
#pragma unroll
        for (int i = 0; i < ROWS / 4; ++i) {
            const int r = wave * (ROWS / 4) + i;
#pragma unroll
            for (int c = 0; c < QN / 256; ++c) {
                const size_t off = (size_t)(b0 + r) * N_MLP + c * 256 + lane * 4;
                __builtin_amdgcn_global_load_lds(
                    (gbl_void*)(gx + off),
                    (lds_void*)&xbuf[r * QN + c * 256 + lane * 4], 16, 0, 0);
                __builtin_amdgcn_global_load_lds(
                    (gbl_void*)(ga + off),
                    (lds_void*)&abuf[r * QN + c * 256 + lane * 4], 16, 0, 0);
            }
        }
        __syncthreads();   // drain: tile resident (also fences prev tile's red[])

        // ---- compute from LDS: float2 per thread per row (ds_read_b64) ----
        const float2* xb = reinterpret_cast<const float2*>(xbuf);
        const float2* ab = reinterpret_cast<const float2*>(abuf);
        float acc[ROWS];
#pragma unroll
        for (int r = 0; r < ROWS; ++r) {
            const float2 xv = xb[r * (QN / 2) + t];
            const float2 av = ab[r * (QN / 2) + t];
            float s = bsum;
            // MLP n0: inputs (xv.x, av.x)
            float h0 = fmaf(wa0.x, xv.x, fmaf(wa0.y, av.x, b10.x));
            float h1 = fmaf(wa0.z, xv.x, fmaf(wa0.w, av.x, b10.y));
            float h2 = fmaf(wb0.x, xv.x, fmaf(wb0.y, av.x, b10.z));
            float h3 = fmaf(wb0.z, xv.x, fmaf(wb0.w, av.x, b10.w));
            s = fmaf(w20.x, fmaxf(h0, 0.0f), s);
            s = fmaf(w20.y, fmaxf(h1, 0.0f), s);
            s = fmaf(w20.z, fmaxf(h2, 0.0f), s);
            s = fmaf(w20.w, fmaxf(h3, 0.0f), s);
            // MLP n0+1: inputs (xv.y, av.y)
            h0 = fmaf(wa1.x, xv.y, fmaf(wa1.y, av.y, b11.x));
            h1 = fmaf(wa1.z, xv.y, fmaf(wa1.w, av.y, b11.y));
            h2 = fmaf(wb1.x, xv.y, fmaf(wb1.y, av.y, b11.z));
            h3 = fmaf(wb1.z, xv.y, fmaf(wb1.w, av.y, b11.w));
            s = fmaf(w21.x, fmaxf(h0, 0.0f), s);
            s = fmaf(w21.y, fmaxf(h1, 0.0f), s);
            s = fmaf(w21.z, fmaxf(h2, 0.0f), s);
            s = fmaf(w21.w, fmaxf(h3, 0.0f), s);
            acc[r] = s;
        }

        // ---- reduce each row across 256 threads ----
#pragma unroll
        for (int r = 0; r < ROWS; ++r) {
            float v = acc[r];
            v += __shfl_down(v, 32);
            v += __shfl_down(v, 16);
            v += __shfl_down(v, 8);
            v += __shfl_down(v, 4);
            v += __shfl_down(v, 2);
            v += __shfl_down(v, 1);
            if (lane == 0) red[wave][r] = v;
        }
        __syncthreads();
        if (t < ROWS) {
            float s = (red[0][t] + red[1][t]) + (red[2][t] + red[3][t]);
            atomicAdd(out + b0 + t, s * (1.0f / (float)N_MLP));
        }
        // next tile's first __syncthreads orders red[] reads vs re-writes,
        // and buffer re-staging vs this tile's LDS reads (all pre-barrier).
    }
}

extern "C" void kernel_launch(void* const* d_in, const int* in_sizes, int n_in,
                              void* d_out, int out_size, void* d_ws, size_t ws_size,
                              hipStream_t stream) {
    const float* x  = (const float*)d_in[0];
    const float* xa = (const float*)d_in[1];
    const float* W1 = (const float*)d_in[2];
    const float* b1 = (const float*)d_in[3];
    const float* W2 = (const float*)d_in[4];
    const float* b2 = (const float*)d_in[5];
    float* out = (float*)d_out;

    zero_out_kernel<<<BATCH / 256, 256, 0, stream>>>(out);
    disc_mlp_kernel<<<NBLK, NTHREADS, 0, stream>>>(x, xa, W1, b1, W2, b2, out);
}